// Round 1
// baseline (229.030 us; speedup 1.0000x reference)
//
#include <hip/hip_runtime.h>
#include <hip/hip_bf16.h>

// MHA: B=2 T=2048 H=1024 NH=16 HD=64. All matmuls via bf16 MFMA 16x16x32.
#define Bb 2
#define Tt 2048
#define Hh 1024
#define NHh 16
#define HDd 64

typedef short bf16x8 __attribute__((ext_vector_type(8)));
typedef float f32x4 __attribute__((ext_vector_type(4)));
typedef unsigned short u16;
typedef u16 u16x4v __attribute__((ext_vector_type(4)));

__device__ __forceinline__ u16 f2b(float x) {
  unsigned u = __builtin_bit_cast(unsigned, x);
  u += 0x7FFFu + ((u >> 16) & 1u);   // RNE
  return (u16)(u >> 16);
}

// ---------------- fp32 -> bf16 conversion (vectorized) ----------------
__global__ __launch_bounds__(256) void cvt_kernel(const float* __restrict__ src,
                                                  u16* __restrict__ dst, int n4) {
  int i = blockIdx.x * blockDim.x + threadIdx.x;
  int stride = gridDim.x * blockDim.x;
  for (; i < n4; i += stride) {
    float4 v = ((const float4*)src)[i];
    u16x4v o;
    o.x = f2b(v.x); o.y = f2b(v.y); o.z = f2b(v.z); o.w = f2b(v.w);
    ((u16x4v*)dst)[i] = o;
  }
}

// ---------------- shared GEMM body: C[4096,1024] = A * W^T + bias ----------------
// A [4096,1024] bf16 row-major, W [1024,1024] bf16 row-major (B^T convention).
// 128x128 tile, BK=64, 4 waves (2x2), each wave 64x64 via 4x4 frags of 16x16x32.
// LDS XOR swizzle byte ^= (row&7)<<4 applied on BOTH ds_write staging and ds_read.
// MODE 0: bf16 out scattered to [B,NH,T,HD]; MODE 1: fp32 out row-major [4096,1024].
template<int MODE>
__device__ __forceinline__ void gemm_body(const u16* __restrict__ A,
                                          const u16* __restrict__ W,
                                          const float* __restrict__ bias,
                                          void* __restrict__ Cout,
                                          u16* lA, u16* lB) {
  const int tid = threadIdx.x;
  const int lane = tid & 63;
  const int wid = tid >> 6;
  const int wr = wid >> 1, wc = wid & 1;
  const int g = lane >> 4, fr = lane & 15;
  const int mt = blockIdx.y, nt = blockIdx.x;

  f32x4 acc[4][4];
#pragma unroll
  for (int m = 0; m < 4; ++m)
#pragma unroll
    for (int n = 0; n < 4; ++n)
      acc[m][n] = (f32x4){0.f, 0.f, 0.f, 0.f};

  const int srow = tid >> 3;        // 0..31
  const int scol = (tid & 7) * 8;   // element col, 0..56

  for (int kt = 0; kt < Hh; kt += 64) {
#pragma unroll
    for (int ps = 0; ps < 4; ++ps) {
      int row = ps * 32 + srow;
      bf16x8 va = *(const bf16x8*)(A + (size_t)(mt * 128 + row) * Hh + kt + scol);
      bf16x8 vb = *(const bf16x8*)(W + (size_t)(nt * 128 + row) * Hh + kt + scol);
      int la = row * 128 + ((scol * 2) ^ ((row & 7) << 4));
      *(bf16x8*)((char*)lA + la) = va;
      *(bf16x8*)((char*)lB + la) = vb;
    }
    __syncthreads();
    bf16x8 af[4][2], bfv[4][2];
#pragma unroll
    for (int m = 0; m < 4; ++m)
#pragma unroll
      for (int ks = 0; ks < 2; ++ks) {
        int ra = wr * 64 + m * 16 + fr;
        int rb = wc * 64 + m * 16 + fr;
        int cb = ks * 64 + g * 16;
        af[m][ks]  = *(const bf16x8*)((const char*)lA + ra * 128 + (cb ^ ((ra & 7) << 4)));
        bfv[m][ks] = *(const bf16x8*)((const char*)lB + rb * 128 + (cb ^ ((rb & 7) << 4)));
      }
#pragma unroll
    for (int m = 0; m < 4; ++m)
#pragma unroll
      for (int n = 0; n < 4; ++n)
#pragma unroll
        for (int ks = 0; ks < 2; ++ks)
          acc[m][n] = __builtin_amdgcn_mfma_f32_16x16x32_bf16(af[m][ks], bfv[n][ks],
                                                              acc[m][n], 0, 0, 0);
    __syncthreads();
  }

#pragma unroll
  for (int n = 0; n < 4; ++n) {
    int Cc = nt * 128 + wc * 64 + n * 16 + fr;
    float bv = bias[Cc];
#pragma unroll
    for (int m = 0; m < 4; ++m) {
#pragma unroll
      for (int j = 0; j < 4; ++j) {
        int R = mt * 128 + wr * 64 + m * 16 + g * 4 + j;
        float val = acc[m][n][j] + bv;
        if (MODE == 0) {
          int bb = R >> 11, t = R & (Tt - 1);
          int h = Cc >> 6, d = Cc & 63;
          ((u16*)Cout)[(((size_t)(bb * NHh + h) * Tt + t) << 6) + d] = f2b(val);
        } else {
          ((float*)Cout)[(size_t)R * Hh + Cc] = val;
        }
      }
    }
  }
}

__global__ __launch_bounds__(256) void proj_qkv_kernel(
    const u16* __restrict__ qb, const u16* __restrict__ kb, const u16* __restrict__ vb,
    const u16* __restrict__ wqb, const u16* __restrict__ wkb, const u16* __restrict__ wvb,
    const float* __restrict__ biq, const float* __restrict__ bik, const float* __restrict__ biv,
    u16* __restrict__ Qp, u16* __restrict__ Kp, u16* __restrict__ Vp) {
  __shared__ u16 lA[128 * 64];
  __shared__ u16 lB[128 * 64];
  const int z = blockIdx.z;
  const u16* A = (z == 0) ? qb : (z == 1) ? kb : vb;
  const u16* W = (z == 0) ? wqb : (z == 1) ? wkb : wvb;
  const float* bi = (z == 0) ? biq : (z == 1) ? bik : biv;
  u16* O = (z == 0) ? Qp : (z == 1) ? Kp : Vp;
  gemm_body<0>(A, W, bi, O, lA, lB);
}

__global__ __launch_bounds__(256) void gemm_out_kernel(
    const u16* __restrict__ A, const u16* __restrict__ W,
    const float* __restrict__ bias, float* __restrict__ Cout) {
  __shared__ u16 lA[128 * 64];
  __shared__ u16 lB[128 * 64];
  gemm_body<1>(A, W, bias, Cout, lA, lB);
}

// ---------------- V transpose: [B,NH,T,HD] -> [B,NH,HD,T] ----------------
__global__ __launch_bounds__(256) void transpose_v(const u16* __restrict__ Vp,
                                                   u16* __restrict__ Vt) {
  __shared__ u16 tile[64][72];   // +8 pad breaks bank alignment
  const int tt = blockIdx.x, bh = blockIdx.y;
  const int tid = threadIdx.x;
  const int r = tid >> 3, c = (tid & 7) * 8;
#pragma unroll
  for (int i = 0; i < 2; ++i) {
    int row = i * 32 + r;   // t within tile
    bf16x8 v = *(const bf16x8*)(Vp + ((size_t)(bh * Tt + tt * 64 + row) << 6) + c);
    *(bf16x8*)&tile[row][c] = v;
  }
  __syncthreads();
#pragma unroll
  for (int i = 0; i < 2; ++i) {
    int idx = tid + i * 256;
    int d = idx >> 3;            // 0..63
    int tc = (idx & 7) * 8;      // t chunk
    bf16x8 o;
#pragma unroll
    for (int e = 0; e < 8; ++e) o[e] = (short)tile[tc + e][d];
    *(bf16x8*)(Vt + ((size_t)(bh * 64 + d) << 11) + tt * 64 + tc) = o;
  }
}

// ---------------- flash attention (causal), 1 block = (bh, 64-row q tile) ----------------
__global__ __launch_bounds__(256) void attn_kernel(const u16* __restrict__ Qp,
                                                   const u16* __restrict__ Kp,
                                                   const u16* __restrict__ Vt,
                                                   u16* __restrict__ AO) {
  __shared__ u16 lQ[64 * 64];
  __shared__ u16 lK[64 * 64];
  __shared__ u16 lV[64 * 64];   // [d][kv]
  __shared__ u16 lP[64 * 64];
  const int tid = threadIdx.x;
  const int lane = tid & 63;
  const int w = tid >> 6;
  const int g = lane >> 4, fr = lane & 15;
  const int qt = blockIdx.x, bh = blockIdx.y;

  const int srow = tid >> 3;
  const int scol = (tid & 7) * 8;

  // stage Q tile (swizzled)
#pragma unroll
  for (int ps = 0; ps < 2; ++ps) {
    int r = ps * 32 + srow;
    bf16x8 v = *(const bf16x8*)(Qp + ((size_t)(bh * Tt + qt * 64 + r) << 6) + scol);
    *(bf16x8*)((char*)lQ + r * 128 + ((scol * 2) ^ ((r & 7) << 4))) = v;
  }
  __syncthreads();
  bf16x8 aq[2];
#pragma unroll
  for (int ks = 0; ks < 2; ++ks) {
    int row = w * 16 + fr;
    int cb = ks * 64 + g * 16;
    aq[ks] = *(const bf16x8*)((const char*)lQ + row * 128 + (cb ^ ((row & 7) << 4)));
  }

  float m_s[4], l_s[4];
  f32x4 acc_o[4];
#pragma unroll
  for (int j = 0; j < 4; ++j) { m_s[j] = -1e30f; l_s[j] = 0.f; }
#pragma unroll
  for (int nd = 0; nd < 4; ++nd) acc_o[nd] = (f32x4){0.f, 0.f, 0.f, 0.f};

  for (int jt = 0; jt <= qt; ++jt) {
    // stage K [kv][d] and V^T [d][kv] tiles
#pragma unroll
    for (int ps = 0; ps < 2; ++ps) {
      int r = ps * 32 + srow;
      bf16x8 vk = *(const bf16x8*)(Kp + ((size_t)(bh * Tt + jt * 64 + r) << 6) + scol);
      bf16x8 vv = *(const bf16x8*)(Vt + ((size_t)(bh * 64 + r) << 11) + jt * 64 + scol);
      int la = r * 128 + ((scol * 2) ^ ((r & 7) << 4));
      *(bf16x8*)((char*)lK + la) = vk;
      *(bf16x8*)((char*)lV + la) = vv;
    }
    __syncthreads();

    // S = Q K^T  (wave w owns q rows w*16..+15; C: col=kv=fr, row=g*4+j)
    f32x4 s[4];
#pragma unroll
    for (int n = 0; n < 4; ++n) {
      s[n] = (f32x4){0.f, 0.f, 0.f, 0.f};
#pragma unroll
      for (int ks = 0; ks < 2; ++ks) {
        int rb = n * 16 + fr;
        int cb = ks * 64 + g * 16;
        bf16x8 bk = *(const bf16x8*)((const char*)lK + rb * 128 + (cb ^ ((rb & 7) << 4)));
        s[n] = __builtin_amdgcn_mfma_f32_16x16x32_bf16(aq[ks], bk, s[n], 0, 0, 0);
      }
    }

    const bool diag = (jt == qt);
    float p[4][4];
#pragma unroll
    for (int n = 0; n < 4; ++n)
#pragma unroll
      for (int j = 0; j < 4; ++j) {
        float sv = s[n][j] * 0.125f;
        if (diag && (n * 16 + fr) > (w * 16 + g * 4 + j)) sv = -1e30f;
        s[n][j] = sv;
      }
    // online softmax per q-row (row j lives on the 16 lanes of this g-group)
#pragma unroll
    for (int j = 0; j < 4; ++j) {
      float tm = fmaxf(fmaxf(s[0][j], s[1][j]), fmaxf(s[2][j], s[3][j]));
#pragma unroll
      for (int xm = 1; xm < 16; xm <<= 1) tm = fmaxf(tm, __shfl_xor(tm, xm));
      float mn = fmaxf(m_s[j], tm);
      float sc = __expf(m_s[j] - mn);
      float rs = 0.f;
#pragma unroll
      for (int n = 0; n < 4; ++n) { p[n][j] = __expf(s[n][j] - mn); rs += p[n][j]; }
#pragma unroll
      for (int xm = 1; xm < 16; xm <<= 1) rs += __shfl_xor(rs, xm);
      l_s[j] = l_s[j] * sc + rs;
      m_s[j] = mn;
#pragma unroll
      for (int nd = 0; nd < 4; ++nd) acc_o[nd][j] *= sc;
    }
    // write P (bf16, swizzled). Each wave writes/reads ONLY its own 16 rows -> no barrier.
#pragma unroll
    for (int n = 0; n < 4; ++n) {
      int colb = (n * 16 + fr) * 2;
#pragma unroll
      for (int j = 0; j < 4; ++j) {
        int row = w * 16 + g * 4 + j;
        *(u16*)((char*)lP + row * 128 + (colb ^ ((row & 7) << 4))) = f2b(p[n][j]);
      }
    }
    // PV: O += P * V   (A = P rows, B = V^T rows from lV)
    bf16x8 pa[2];
#pragma unroll
    for (int ks = 0; ks < 2; ++ks) {
      int row = w * 16 + fr;
      int cb = ks * 64 + g * 16;
      pa[ks] = *(const bf16x8*)((const char*)lP + row * 128 + (cb ^ ((row & 7) << 4)));
    }
#pragma unroll
    for (int nd = 0; nd < 4; ++nd)
#pragma unroll
      for (int ks = 0; ks < 2; ++ks) {
        int rb = nd * 16 + fr;
        int cb = ks * 64 + g * 16;
        bf16x8 bv = *(const bf16x8*)((const char*)lV + rb * 128 + (cb ^ ((rb & 7) << 4)));
        acc_o[nd] = __builtin_amdgcn_mfma_f32_16x16x32_bf16(pa[ks], bv, acc_o[nd], 0, 0, 0);
      }
    __syncthreads();   // protect lK/lV (and lP) before next staging
  }

  // epilogue: normalize and merge heads into AO [B,T,H] bf16
  const int b = bh >> 4, h = bh & 15;
#pragma unroll
  for (int j = 0; j < 4; ++j) {
    float inv = 1.0f / l_s[j];
    int q = qt * 64 + w * 16 + g * 4 + j;
    size_t base = ((size_t)(b * Tt + q) << 10) + h * 64;
#pragma unroll
    for (int nd = 0; nd < 4; ++nd)
      AO[base + nd * 16 + fr] = f2b(acc_o[nd][j] * inv);
  }
}

extern "C" void kernel_launch(void* const* d_in, const int* in_sizes, int n_in,
                              void* d_out, int out_size, void* d_ws, size_t ws_size,
                              hipStream_t stream) {
  const float* q   = (const float*)d_in[0];
  const float* k   = (const float*)d_in[1];
  const float* v   = (const float*)d_in[2];
  // d_in[3] = mask (known causal tril; unused)
  const float* wq  = (const float*)d_in[4];
  const float* bq  = (const float*)d_in[5];
  const float* wk  = (const float*)d_in[6];
  const float* bk  = (const float*)d_in[7];
  const float* wv  = (const float*)d_in[8];
  const float* bv  = (const float*)d_in[9];
  const float* wo  = (const float*)d_in[10];
  const float* bo  = (const float*)d_in[11];

  char* ws = (char*)d_ws;
  const size_t SZB = (size_t)Bb * Tt * Hh * 2;  // 8.39 MB (bf16 activation)
  const size_t WB  = (size_t)Hh * Hh * 2;       // 2.10 MB (bf16 weight)
  // Peak ws use: 6*SZB + 4*WB = 56 MB. Vt/AO alias qb/kb (dead after projections).
  u16* qb  = (u16*)(ws);
  u16* kb  = (u16*)(ws + SZB);
  u16* vb  = (u16*)(ws + 2 * SZB);
  u16* wqb = (u16*)(ws + 3 * SZB);
  u16* wkb = (u16*)(ws + 3 * SZB + WB);
  u16* wvb = (u16*)(ws + 3 * SZB + 2 * WB);
  u16* wob = (u16*)(ws + 3 * SZB + 3 * WB);
  u16* Qp  = (u16*)(ws + 3 * SZB + 4 * WB);
  u16* Kp  = (u16*)(ws + 4 * SZB + 4 * WB);
  u16* Vp  = (u16*)(ws + 5 * SZB + 4 * WB);
  u16* Vt  = qb;   // reuse
  u16* AO  = kb;   // reuse

  const int N4_IN = (Bb * Tt * Hh) / 4;
  const int N4_W  = (Hh * Hh) / 4;
  cvt_kernel<<<1024, 256, 0, stream>>>(q, qb, N4_IN);
  cvt_kernel<<<1024, 256, 0, stream>>>(k, kb, N4_IN);
  cvt_kernel<<<1024, 256, 0, stream>>>(v, vb, N4_IN);
  cvt_kernel<<<256, 256, 0, stream>>>(wq, wqb, N4_W);
  cvt_kernel<<<256, 256, 0, stream>>>(wk, wkb, N4_W);
  cvt_kernel<<<256, 256, 0, stream>>>(wv, wvb, N4_W);
  cvt_kernel<<<256, 256, 0, stream>>>(wo, wob, N4_W);

  proj_qkv_kernel<<<dim3(Hh / 128, (Bb * Tt) / 128, 3), 256, 0, stream>>>(
      qb, kb, vb, wqb, wkb, wvb, bq, bk, bv, Qp, Kp, Vp);

  transpose_v<<<dim3(Tt / 64, Bb * NHh), 256, 0, stream>>>(Vp, Vt);

  attn_kernel<<<dim3(Tt / 64, Bb * NHh), 256, 0, stream>>>(Qp, Kp, Vt, AO);

  gemm_out_kernel<<<dim3(Hh / 128, (Bb * Tt) / 128), 256, 0, stream>>>(
      AO, wob, bo, (float*)d_out);
}

// Round 2
// 170.927 us; speedup vs baseline: 1.3399x; 1.3399x over previous
//
#include <hip/hip_runtime.h>
#include <hip/hip_bf16.h>

// MHA: B=2 T=2048 H=1024 NH=16 HD=64. All matmuls via bf16 MFMA 16x16x32.
#define Bb 2
#define Tt 2048
#define Hh 1024
#define NHh 16
#define HDd 64

typedef short bf16x8 __attribute__((ext_vector_type(8)));
typedef float f32x4 __attribute__((ext_vector_type(4)));
typedef unsigned short u16;
typedef u16 u16x4v __attribute__((ext_vector_type(4)));

__device__ __forceinline__ u16 f2b(float x) {
  unsigned u = __builtin_bit_cast(unsigned, x);
  u += 0x7FFFu + ((u >> 16) & 1u);   // RNE
  return (u16)(u >> 16);
}

// ---------------- fp32 -> bf16 conversion (batched, vectorized) ----------------
__global__ __launch_bounds__(256) void cvt3_kernel(const float* __restrict__ s0,
                                                   const float* __restrict__ s1,
                                                   const float* __restrict__ s2,
                                                   u16* __restrict__ d0,
                                                   u16* __restrict__ d1,
                                                   u16* __restrict__ d2, int n4) {
  const int which = blockIdx.y;
  const float* src = which == 0 ? s0 : which == 1 ? s1 : s2;
  u16* dst = which == 0 ? d0 : which == 1 ? d1 : d2;
  int i = blockIdx.x * blockDim.x + threadIdx.x;
  int stride = gridDim.x * blockDim.x;
  for (; i < n4; i += stride) {
    float4 v = ((const float4*)src)[i];
    u16x4v o;
    o.x = f2b(v.x); o.y = f2b(v.y); o.z = f2b(v.z); o.w = f2b(v.w);
    ((u16x4v*)dst)[i] = o;
  }
}

__global__ __launch_bounds__(256) void cvt4_kernel(const float* __restrict__ s0,
                                                   const float* __restrict__ s1,
                                                   const float* __restrict__ s2,
                                                   const float* __restrict__ s3,
                                                   u16* __restrict__ d0,
                                                   u16* __restrict__ d1,
                                                   u16* __restrict__ d2,
                                                   u16* __restrict__ d3, int n4) {
  const int which = blockIdx.y;
  const float* src = which == 0 ? s0 : which == 1 ? s1 : which == 2 ? s2 : s3;
  u16* dst = which == 0 ? d0 : which == 1 ? d1 : which == 2 ? d2 : d3;
  int i = blockIdx.x * blockDim.x + threadIdx.x;
  int stride = gridDim.x * blockDim.x;
  for (; i < n4; i += stride) {
    float4 v = ((const float4*)src)[i];
    u16x4v o;
    o.x = f2b(v.x); o.y = f2b(v.y); o.z = f2b(v.z); o.w = f2b(v.w);
    ((u16x4v*)dst)[i] = o;
  }
}

// ---------------- shared GEMM body: C[4096,1024] = A * W^T + bias ----------------
// 128x128 tile, BK=64, 4 waves (2x2), each wave 64x64 via 4x4 frags of 16x16x32.
// LDS XOR swizzle byte ^= (row&7)<<4 applied on BOTH ds_write staging and ds_read.
// mode 0: bf16 out scattered to [B,NH,T,HD]
// mode 1: fp32 out row-major [4096,1024]
// mode 2: bf16 out scattered to V^T layout [B,NH,HD,T]
__device__ __forceinline__ void gemm_body(const u16* __restrict__ A,
                                          const u16* __restrict__ W,
                                          const float* __restrict__ bias,
                                          void* __restrict__ Cout,
                                          u16* lA, u16* lB, int mode) {
  const int tid = threadIdx.x;
  const int lane = tid & 63;
  const int wid = tid >> 6;
  const int wr = wid >> 1, wc = wid & 1;
  const int g = lane >> 4, fr = lane & 15;
  const int mt = blockIdx.y, nt = blockIdx.x;

  f32x4 acc[4][4];
#pragma unroll
  for (int m = 0; m < 4; ++m)
#pragma unroll
    for (int n = 0; n < 4; ++n)
      acc[m][n] = (f32x4){0.f, 0.f, 0.f, 0.f};

  const int srow = tid >> 3;        // 0..31
  const int scol = (tid & 7) * 8;   // element col, 0..56

  for (int kt = 0; kt < Hh; kt += 64) {
#pragma unroll
    for (int ps = 0; ps < 4; ++ps) {
      int row = ps * 32 + srow;
      bf16x8 va = *(const bf16x8*)(A + (size_t)(mt * 128 + row) * Hh + kt + scol);
      bf16x8 vb = *(const bf16x8*)(W + (size_t)(nt * 128 + row) * Hh + kt + scol);
      int la = row * 128 + ((scol * 2) ^ ((row & 7) << 4));
      *(bf16x8*)((char*)lA + la) = va;
      *(bf16x8*)((char*)lB + la) = vb;
    }
    __syncthreads();
    bf16x8 af[4][2], bfv[4][2];
#pragma unroll
    for (int m = 0; m < 4; ++m)
#pragma unroll
      for (int ks = 0; ks < 2; ++ks) {
        int ra = wr * 64 + m * 16 + fr;
        int rb = wc * 64 + m * 16 + fr;
        int cb = ks * 64 + g * 16;
        af[m][ks]  = *(const bf16x8*)((const char*)lA + ra * 128 + (cb ^ ((ra & 7) << 4)));
        bfv[m][ks] = *(const bf16x8*)((const char*)lB + rb * 128 + (cb ^ ((rb & 7) << 4)));
      }
#pragma unroll
    for (int m = 0; m < 4; ++m)
#pragma unroll
      for (int n = 0; n < 4; ++n)
#pragma unroll
        for (int ks = 0; ks < 2; ++ks)
          acc[m][n] = __builtin_amdgcn_mfma_f32_16x16x32_bf16(af[m][ks], bfv[n][ks],
                                                              acc[m][n], 0, 0, 0);
    __syncthreads();
  }

#pragma unroll
  for (int n = 0; n < 4; ++n) {
    int Cc = nt * 128 + wc * 64 + n * 16 + fr;
    float bv = bias[Cc];
#pragma unroll
    for (int m = 0; m < 4; ++m) {
#pragma unroll
      for (int j = 0; j < 4; ++j) {
        int R = mt * 128 + wr * 64 + m * 16 + g * 4 + j;
        float val = acc[m][n][j] + bv;
        if (mode == 0) {
          int bb = R >> 11, t = R & (Tt - 1);
          int h = Cc >> 6, d = Cc & 63;
          ((u16*)Cout)[(((size_t)(bb * NHh + h) * Tt + t) << 6) + d] = f2b(val);
        } else if (mode == 2) {
          int bb = R >> 11, t = R & (Tt - 1);
          int h = Cc >> 6, d = Cc & 63;
          ((u16*)Cout)[(((size_t)(bb * NHh + h) * 64 + d) << 11) + t] = f2b(val);
        } else {
          ((float*)Cout)[(size_t)R * Hh + Cc] = val;
        }
      }
    }
  }
}

__global__ __launch_bounds__(256) void proj_qkv_kernel(
    const u16* __restrict__ qb, const u16* __restrict__ kb, const u16* __restrict__ vb,
    const u16* __restrict__ wqb, const u16* __restrict__ wkb, const u16* __restrict__ wvb,
    const float* __restrict__ biq, const float* __restrict__ bik, const float* __restrict__ biv,
    u16* __restrict__ Qp, u16* __restrict__ Kp, u16* __restrict__ Vt) {
  __shared__ u16 lA[128 * 64];
  __shared__ u16 lB[128 * 64];
  const int z = blockIdx.z;
  const u16* A = (z == 0) ? qb : (z == 1) ? kb : vb;
  const u16* W = (z == 0) ? wqb : (z == 1) ? wkb : wvb;
  const float* bi = (z == 0) ? biq : (z == 1) ? bik : biv;
  u16* O = (z == 0) ? Qp : (z == 1) ? Kp : Vt;
  gemm_body(A, W, bi, O, lA, lB, (z == 2) ? 2 : 0);
}

__global__ __launch_bounds__(256) void gemm_out_kernel(
    const u16* __restrict__ A, const u16* __restrict__ W,
    const float* __restrict__ bias, float* __restrict__ Cout) {
  __shared__ u16 lA[128 * 64];
  __shared__ u16 lB[128 * 64];
  gemm_body(A, W, bias, Cout, lA, lB, 1);
}

// ---------------- flash attention (causal), swapped-QK^T, async-staged ----------------
// 1 block = (bh, 64-row q tile), 4 waves, wave w owns q rows w*16..w*16+15.
// Swapped QK: s = mfma(K_frag, Q_frag) -> lane holds 16 S values of q-row (lane&15).
// Softmax: in-lane reduce + 2 shfl_xor. P -> LDS (4x ds_write_b64) -> PV A-frag.
__global__ __launch_bounds__(256) void attn_kernel(const u16* __restrict__ Qp,
                                                   const u16* __restrict__ Kp,
                                                   const u16* __restrict__ Vt,
                                                   u16* __restrict__ AO) {
  __shared__ u16 lK[64 * 64];
  __shared__ u16 lV[64 * 64];   // [d][kv]
  __shared__ u16 lP[64 * 64];
  const int tid = threadIdx.x;
  const int lane = tid & 63;
  const int w = tid >> 6;
  const int g = lane >> 4, fr = lane & 15;
  const int qt = blockIdx.x, bh = blockIdx.y;

  // Q fragment (B operand): q = w*16+fr, d = 32*ks + g*8 + 0..7 (straight from global)
  bf16x8 qf[2];
  {
    const u16* qrow = Qp + (((size_t)bh * Tt + qt * 64 + w * 16 + fr) << 6) + g * 8;
    qf[0] = *(const bf16x8*)(qrow);
    qf[1] = *(const bf16x8*)(qrow + 32);
  }

  const int srow = tid >> 3;        // 0..31
  const int scol = (tid & 7) * 8;

  // prologue: tile 0 K/V into regs
  bf16x8 rk[2], rv[2];
#pragma unroll
  for (int ps = 0; ps < 2; ++ps) {
    int r = ps * 32 + srow;
    rk[ps] = *(const bf16x8*)(Kp + (((size_t)bh * Tt + r) << 6) + scol);
    rv[ps] = *(const bf16x8*)(Vt + (((size_t)bh * 64 + r) << 11) + scol);
  }

  float m_r = -1e30f, l_r = 0.f;    // row state for q-row (w*16 + fr)
  f32x4 acc[4];                     // acc[nd][j]: d = nd*16+fr, q = w*16 + g*4+j
#pragma unroll
  for (int nd = 0; nd < 4; ++nd) acc[nd] = (f32x4){0.f, 0.f, 0.f, 0.f};

  const int prow = w * 16 + fr;     // this lane's P row
  const int psw = (prow & 7) << 4;

  for (int jt = 0; jt <= qt; ++jt) {
    // commit staged regs to LDS
#pragma unroll
    for (int ps = 0; ps < 2; ++ps) {
      int r = ps * 32 + srow;
      int la = r * 128 + ((scol * 2) ^ ((r & 7) << 4));
      *(bf16x8*)((char*)lK + la) = rk[ps];
      *(bf16x8*)((char*)lV + la) = rv[ps];
    }
    __syncthreads();
    // async: issue next tile's loads now; consumed after next barrier
    if (jt < qt) {
#pragma unroll
      for (int ps = 0; ps < 2; ++ps) {
        int r = ps * 32 + srow;
        rk[ps] = *(const bf16x8*)(Kp + (((size_t)bh * Tt + (jt + 1) * 64 + r) << 6) + scol);
        rv[ps] = *(const bf16x8*)(Vt + (((size_t)bh * 64 + r) << 11) + (jt + 1) * 64 + scol);
      }
    }
    // QK^T swapped: s[n][r]: k = 16n + g*4 + r, q = w*16 + fr
    f32x4 s[4];
#pragma unroll
    for (int n = 0; n < 4; ++n) {
      s[n] = (f32x4){0.f, 0.f, 0.f, 0.f};
#pragma unroll
      for (int ks = 0; ks < 2; ++ks) {
        int rr = n * 16 + fr;
        int cb = ks * 64 + g * 16;
        bf16x8 ak = *(const bf16x8*)((const char*)lK + rr * 128 + (cb ^ ((rr & 7) << 4)));
        s[n] = __builtin_amdgcn_mfma_f32_16x16x32_bf16(ak, qf[ks], s[n], 0, 0, 0);
      }
    }
    // scale + causal mask + row max (in-lane + 2 shuffles)
    const bool diag = (jt == qt);
    float tm = -1e30f;
#pragma unroll
    for (int n = 0; n < 4; ++n)
#pragma unroll
      for (int r = 0; r < 4; ++r) {
        float sv = s[n][r] * 0.125f;
        if (diag && (n * 16 + g * 4 + r) > prow) sv = -1e30f;
        s[n][r] = sv;
        tm = fmaxf(tm, sv);
      }
    tm = fmaxf(tm, __shfl_xor(tm, 16));
    tm = fmaxf(tm, __shfl_xor(tm, 32));
    float mn = fmaxf(m_r, tm);
    float sc = __expf(m_r - mn);
    m_r = mn;
    float rs = 0.f;
    u16x4v pw[4];
#pragma unroll
    for (int n = 0; n < 4; ++n)
#pragma unroll
      for (int r = 0; r < 4; ++r) {
        float p = __expf(s[n][r] - mn);
        rs += p;
        pw[n][r] = f2b(p);
      }
    rs += __shfl_xor(rs, 16);
    rs += __shfl_xor(rs, 32);
    l_r = l_r * sc + rs;
    // write P row (wave-private rows: no barrier needed before same-wave read)
    {
      char* base = (char*)lP + prow * 128;
#pragma unroll
      for (int n = 0; n < 4; ++n)
        *(u16x4v*)(base + ((32 * n + 8 * g) ^ psw)) = pw[n];
    }
    // broadcast rescale factors to PV-acc row owners (rows g*4+j)
    float scj[4];
#pragma unroll
    for (int j = 0; j < 4; ++j) scj[j] = __shfl(sc, g * 4 + j);
#pragma unroll
    for (int nd = 0; nd < 4; ++nd)
#pragma unroll
      for (int j = 0; j < 4; ++j) acc[nd][j] *= scj[j];
    // PV: A = P (rows w*16+fr), B = V^T rows from lV
    bf16x8 pa[2];
#pragma unroll
    for (int ks = 0; ks < 2; ++ks)
      pa[ks] = *(const bf16x8*)((const char*)lP + prow * 128 + ((ks * 64 + g * 16) ^ psw));
#pragma unroll
    for (int nd = 0; nd < 4; ++nd)
#pragma unroll
      for (int ks = 0; ks < 2; ++ks) {
        int rr = nd * 16 + fr;
        int cb = ks * 64 + g * 16;
        bf16x8 bv = *(const bf16x8*)((const char*)lV + rr * 128 + (cb ^ ((rr & 7) << 4)));
        acc[nd] = __builtin_amdgcn_mfma_f32_16x16x32_bf16(pa[ks], bv, acc[nd], 0, 0, 0);
      }
    __syncthreads();   // protect lK/lV before next commit
  }

  // epilogue: normalize (l for rows g*4+j) and merge heads into AO [B,T,H] bf16
  const int b = bh >> 4, h = bh & 15;
  float lj[4];
#pragma unroll
  for (int j = 0; j < 4; ++j) lj[j] = __shfl(l_r, g * 4 + j);
#pragma unroll
  for (int j = 0; j < 4; ++j) {
    float inv = 1.0f / lj[j];
    int qq = qt * 64 + w * 16 + g * 4 + j;
    size_t base = (((size_t)b * Tt + qq) << 10) + h * 64;
#pragma unroll
    for (int nd = 0; nd < 4; ++nd)
      AO[base + nd * 16 + fr] = f2b(acc[nd][j] * inv);
  }
}

extern "C" void kernel_launch(void* const* d_in, const int* in_sizes, int n_in,
                              void* d_out, int out_size, void* d_ws, size_t ws_size,
                              hipStream_t stream) {
  const float* q   = (const float*)d_in[0];
  const float* k   = (const float*)d_in[1];
  const float* v   = (const float*)d_in[2];
  // d_in[3] = mask (known causal tril; unused)
  const float* wq  = (const float*)d_in[4];
  const float* bq  = (const float*)d_in[5];
  const float* wk  = (const float*)d_in[6];
  const float* bk  = (const float*)d_in[7];
  const float* wv  = (const float*)d_in[8];
  const float* bv  = (const float*)d_in[9];
  const float* wo  = (const float*)d_in[10];
  const float* bo  = (const float*)d_in[11];

  char* ws = (char*)d_ws;
  const size_t SZB = (size_t)Bb * Tt * Hh * 2;  // 8.39 MB (bf16 activation)
  const size_t WB  = (size_t)Hh * Hh * 2;       // 2.10 MB (bf16 weight)
  u16* qb  = (u16*)(ws);
  u16* kb  = (u16*)(ws + SZB);
  u16* vb  = (u16*)(ws + 2 * SZB);
  u16* wqb = (u16*)(ws + 3 * SZB);
  u16* wkb = (u16*)(ws + 3 * SZB + WB);
  u16* wvb = (u16*)(ws + 3 * SZB + 2 * WB);
  u16* wob = (u16*)(ws + 3 * SZB + 3 * WB);
  u16* Qp  = (u16*)(ws + 3 * SZB + 4 * WB);
  u16* Kp  = (u16*)(ws + 4 * SZB + 4 * WB);
  u16* Vt  = (u16*)(ws + 5 * SZB + 4 * WB);
  u16* AO  = qb;   // reuse (qb dead after projections)

  const int N4_IN = (Bb * Tt * Hh) / 4;
  const int N4_W  = (Hh * Hh) / 4;
  cvt3_kernel<<<dim3(512, 3), 256, 0, stream>>>(q, k, v, qb, kb, vb, N4_IN);
  cvt4_kernel<<<dim3(128, 4), 256, 0, stream>>>(wq, wk, wv, wo, wqb, wkb, wvb, wob, N4_W);

  proj_qkv_kernel<<<dim3(Hh / 128, (Bb * Tt) / 128, 3), 256, 0, stream>>>(
      qb, kb, vb, wqb, wkb, wvb, bq, bk, bv, Qp, Kp, Vt);

  attn_kernel<<<dim3(Tt / 64, Bb * NHh), 256, 0, stream>>>(Qp, Kp, Vt, AO);

  gemm_out_kernel<<<dim3(Hh / 128, (Bb * Tt) / 128), 256, 0, stream>>>(
      AO, wob, bo, (float*)d_out);
}

// Round 3
// 132.896 us; speedup vs baseline: 1.7234x; 1.2862x over previous
//
#include <hip/hip_runtime.h>
#include <hip/hip_bf16.h>

// MHA: B=2 T=2048 H=1024 NH=16 HD=64. All matmuls via bf16 MFMA 16x16x32.
#define Bb 2
#define Tt 2048
#define Hh 1024
#define NHh 16

typedef short bf16x8 __attribute__((ext_vector_type(8)));
typedef float f32x4 __attribute__((ext_vector_type(4)));
typedef unsigned short u16;
typedef u16 u16x4v __attribute__((ext_vector_type(4)));

// 0.125 * log2(e): folded into w_q/b_q so softmax runs in exp2 domain.
#define QK_SCALE 0.180336880f

#if __has_builtin(__builtin_amdgcn_exp2f)
__device__ __forceinline__ float exp2_fast(float x) { return __builtin_amdgcn_exp2f(x); }
#else
__device__ __forceinline__ float exp2_fast(float x) { return __expf(x * 0.69314718f); }
#endif

__device__ __forceinline__ u16 f2b(float x) {
  unsigned u = __builtin_bit_cast(unsigned, x);
  u += 0x7FFFu + ((u >> 16) & 1u);   // RNE
  return (u16)(u >> 16);
}

// ---------------- fp32 -> bf16 conversion (batched, vectorized) ----------------
__global__ __launch_bounds__(256) void cvt3_kernel(const float* __restrict__ s0,
                                                   const float* __restrict__ s1,
                                                   const float* __restrict__ s2,
                                                   u16* __restrict__ d0,
                                                   u16* __restrict__ d1,
                                                   u16* __restrict__ d2, int n4) {
  const int which = blockIdx.y;
  const float* src = which == 0 ? s0 : which == 1 ? s1 : s2;
  u16* dst = which == 0 ? d0 : which == 1 ? d1 : d2;
  int i = blockIdx.x * blockDim.x + threadIdx.x;
  int stride = gridDim.x * blockDim.x;
  for (; i < n4; i += stride) {
    float4 v = ((const float4*)src)[i];
    u16x4v o;
    o.x = f2b(v.x); o.y = f2b(v.y); o.z = f2b(v.z); o.w = f2b(v.w);
    ((u16x4v*)dst)[i] = o;
  }
}

__global__ __launch_bounds__(256) void cvt4_kernel(const float* __restrict__ s0,
                                                   const float* __restrict__ s1,
                                                   const float* __restrict__ s2,
                                                   const float* __restrict__ s3,
                                                   u16* __restrict__ d0,
                                                   u16* __restrict__ d1,
                                                   u16* __restrict__ d2,
                                                   u16* __restrict__ d3, int n4) {
  const int which = blockIdx.y;
  const float* src = which == 0 ? s0 : which == 1 ? s1 : which == 2 ? s2 : s3;
  u16* dst = which == 0 ? d0 : which == 1 ? d1 : which == 2 ? d2 : d3;
  const float sc = (which == 0) ? QK_SCALE : 1.0f;   // w_q pre-scaled
  int i = blockIdx.x * blockDim.x + threadIdx.x;
  int stride = gridDim.x * blockDim.x;
  for (; i < n4; i += stride) {
    float4 v = ((const float4*)src)[i];
    u16x4v o;
    o.x = f2b(v.x * sc); o.y = f2b(v.y * sc); o.z = f2b(v.z * sc); o.w = f2b(v.w * sc);
    ((u16x4v*)dst)[i] = o;
  }
}

// ---------------- shared GEMM body: C[4096, NT-tiles] = A * W^T + bias*bscale --------
// A [4096,1024] bf16 rm, W [1024,1024] bf16 rm (B^T). Tile 128 x (NF*32), BK=64,
// 4 waves (2x2). Reg-prefetch of next K-tile hides global latency under MFMA.
// MODE 0: bf16 -> [B,NH,T,HD]; MODE 1: fp32 rm; MODE 2: bf16 -> V^T [B,NH,HD,T].
template<int NF, int MODE>
__device__ __forceinline__ void gemm_body(const u16* __restrict__ A,
                                          const u16* __restrict__ W,
                                          const float* __restrict__ bias, float bscale,
                                          void* __restrict__ Cout,
                                          u16* lA, u16* lB) {
  const int tid = threadIdx.x;
  const int lane = tid & 63;
  const int wid = tid >> 6;
  const int wr = wid >> 1, wc = wid & 1;
  const int g = lane >> 4, fr = lane & 15;
  const int mt = blockIdx.y, nt = blockIdx.x;
  constexpr int NT = NF * 32;

  f32x4 acc[4][NF];
#pragma unroll
  for (int m = 0; m < 4; ++m)
#pragma unroll
    for (int n = 0; n < NF; ++n) acc[m][n] = (f32x4){0.f, 0.f, 0.f, 0.f};

  const int srow = tid >> 3;        // 0..31
  const int scol = (tid & 7) * 8;   // element col 0..56

  bf16x8 ra[4], rb[NF];
#pragma unroll
  for (int ps = 0; ps < 4; ++ps)
    ra[ps] = *(const bf16x8*)(A + (size_t)(mt * 128 + ps * 32 + srow) * Hh + scol);
#pragma unroll
  for (int ps = 0; ps < NF; ++ps)
    rb[ps] = *(const bf16x8*)(W + (size_t)(nt * NT + ps * 32 + srow) * Hh + scol);
#pragma unroll
  for (int ps = 0; ps < 4; ++ps) {
    int r = ps * 32 + srow;
    *(bf16x8*)((char*)lA + r * 128 + ((scol * 2) ^ ((r & 7) << 4))) = ra[ps];
  }
#pragma unroll
  for (int ps = 0; ps < NF; ++ps) {
    int r = ps * 32 + srow;
    *(bf16x8*)((char*)lB + r * 128 + ((scol * 2) ^ ((r & 7) << 4))) = rb[ps];
  }
  __syncthreads();

  for (int kt = 0; kt < Hh; kt += 64) {
    if (kt + 64 < Hh) {
#pragma unroll
      for (int ps = 0; ps < 4; ++ps)
        ra[ps] = *(const bf16x8*)(A + (size_t)(mt * 128 + ps * 32 + srow) * Hh + kt + 64 + scol);
#pragma unroll
      for (int ps = 0; ps < NF; ++ps)
        rb[ps] = *(const bf16x8*)(W + (size_t)(nt * NT + ps * 32 + srow) * Hh + kt + 64 + scol);
    }
    bf16x8 af[4][2], bfv[NF][2];
#pragma unroll
    for (int m = 0; m < 4; ++m)
#pragma unroll
      for (int ks = 0; ks < 2; ++ks) {
        int r = wr * 64 + m * 16 + fr;
        af[m][ks] = *(const bf16x8*)((const char*)lA + r * 128 + ((ks * 64 + g * 16) ^ ((r & 7) << 4)));
      }
#pragma unroll
    for (int n = 0; n < NF; ++n)
#pragma unroll
      for (int ks = 0; ks < 2; ++ks) {
        int r = wc * (NT / 2) + n * 16 + fr;
        bfv[n][ks] = *(const bf16x8*)((const char*)lB + r * 128 + ((ks * 64 + g * 16) ^ ((r & 7) << 4)));
      }
#pragma unroll
    for (int m = 0; m < 4; ++m)
#pragma unroll
      for (int n = 0; n < NF; ++n)
#pragma unroll
        for (int ks = 0; ks < 2; ++ks)
          acc[m][n] = __builtin_amdgcn_mfma_f32_16x16x32_bf16(af[m][ks], bfv[n][ks],
                                                              acc[m][n], 0, 0, 0);
    if (kt + 64 < Hh) {
      __syncthreads();
#pragma unroll
      for (int ps = 0; ps < 4; ++ps) {
        int r = ps * 32 + srow;
        *(bf16x8*)((char*)lA + r * 128 + ((scol * 2) ^ ((r & 7) << 4))) = ra[ps];
      }
#pragma unroll
      for (int ps = 0; ps < NF; ++ps) {
        int r = ps * 32 + srow;
        *(bf16x8*)((char*)lB + r * 128 + ((scol * 2) ^ ((r & 7) << 4))) = rb[ps];
      }
      __syncthreads();
    }
  }

#pragma unroll
  for (int n = 0; n < NF; ++n) {
    int Cc = nt * NT + wc * (NT / 2) + n * 16 + fr;
    float bv = bias[Cc] * bscale;
#pragma unroll
    for (int m = 0; m < 4; ++m) {
#pragma unroll
      for (int j = 0; j < 4; ++j) {
        int R = mt * 128 + wr * 64 + m * 16 + g * 4 + j;
        float val = acc[m][n][j] + bv;
        if constexpr (MODE == 0) {
          int bb = R >> 11, t = R & (Tt - 1);
          int h = Cc >> 6, d = Cc & 63;
          ((u16*)Cout)[(((size_t)(bb * NHh + h) * Tt + t) << 6) + d] = f2b(val);
        } else if constexpr (MODE == 2) {
          int bb = R >> 11, t = R & (Tt - 1);
          int h = Cc >> 6, d = Cc & 63;
          ((u16*)Cout)[(((size_t)(bb * NHh + h) * 64 + d) << 11) + t] = f2b(val);
        } else {
          ((float*)Cout)[(size_t)R * Hh + Cc] = val;
        }
      }
    }
  }
}

__global__ __launch_bounds__(256, 2) void proj_qkv_kernel(
    const u16* __restrict__ qb, const u16* __restrict__ kb, const u16* __restrict__ vb,
    const u16* __restrict__ wqb, const u16* __restrict__ wkb, const u16* __restrict__ wvb,
    const float* __restrict__ biq, const float* __restrict__ bik, const float* __restrict__ biv,
    u16* __restrict__ Qp, u16* __restrict__ Kp, u16* __restrict__ Vt) {
  __shared__ u16 lA[128 * 64];
  __shared__ u16 lB[128 * 64];
  const int z = blockIdx.z;
  const u16* A = (z == 0) ? qb : (z == 1) ? kb : vb;
  const u16* W = (z == 0) ? wqb : (z == 1) ? wkb : wvb;
  const float* bi = (z == 0) ? biq : (z == 1) ? bik : biv;
  if (z == 2) gemm_body<4, 2>(A, W, bi, 1.0f, Vt, lA, lB);
  else if (z == 0) gemm_body<4, 0>(A, W, bi, QK_SCALE, Qp, lA, lB);
  else gemm_body<4, 0>(A, W, bi, 1.0f, Kp, lA, lB);
}

__global__ __launch_bounds__(256, 2) void gemm_out_kernel(
    const u16* __restrict__ A, const u16* __restrict__ W,
    const float* __restrict__ bias, float* __restrict__ Cout) {
  __shared__ u16 lA[128 * 64];
  __shared__ u16 lB[64 * 64];
  gemm_body<2, 1>(A, W, bias, 1.0f, Cout, lA, lB);
}

// ---------------- flash attention (causal) ----------------
// QBLK=128 (4 waves x 32 q-rows as 2 halves), KVBLK=64, dbuf K/V LDS, 1 barrier/iter.
// Swapped QK (mfma(K,Q)) -> full q-row in-lane; softmax in exp2 domain (Q pre-scaled).
// 1-D grid of 512, remapped so co-resident block pairs have qt_a + qt_b = 15
// (uniform 34 kv-iters per CU; fixes causal-imbalance idle).
__global__ __launch_bounds__(256, 2) void attn_kernel(const u16* __restrict__ Qp,
                                                      const u16* __restrict__ Kp,
                                                      const u16* __restrict__ Vt,
                                                      u16* __restrict__ AO) {
  __shared__ u16 lK[2 * 64 * 64];
  __shared__ u16 lV[2 * 64 * 64];
  __shared__ u16 lP[128 * 64];
  const int tid = threadIdx.x;
  const int lane = tid & 63;
  const int w = tid >> 6;
  const int g = lane >> 4, fr = lane & 15;
  // balanced remap: CU-resident pair (L, L+256) gets qt and 15-qt
  const int L = blockIdx.x;
  const int idx = L & 255, half = L >> 8;
  const int bh = (half ? 16 : 0) + (idx >> 4);
  const int qt = half ? 15 - (idx & 15) : (idx & 15);
  const int q0 = qt * 128;

  bf16x8 qf[2][2];
#pragma unroll
  for (int h = 0; h < 2; ++h) {
    const u16* qrow = Qp + (((size_t)bh * Tt + q0 + w * 32 + h * 16 + fr) << 6) + g * 8;
    qf[h][0] = *(const bf16x8*)(qrow);
    qf[h][1] = *(const bf16x8*)(qrow + 32);
  }

  const int srow = tid >> 3;
  const int scol = (tid & 7) * 8;
  const int jtmax = 2 * qt + 1;

  // prologue: tile 0 -> regs -> buf0
  bf16x8 rk[2], rv[2];
#pragma unroll
  for (int ps = 0; ps < 2; ++ps) {
    int r = ps * 32 + srow;
    rk[ps] = *(const bf16x8*)(Kp + (((size_t)bh * Tt + r) << 6) + scol);
    rv[ps] = *(const bf16x8*)(Vt + (((size_t)bh * 64 + r) << 11) + scol);
  }
#pragma unroll
  for (int ps = 0; ps < 2; ++ps) {
    int r = ps * 32 + srow;
    int la = r * 128 + ((scol * 2) ^ ((r & 7) << 4));
    *(bf16x8*)((char*)lK + la) = rk[ps];
    *(bf16x8*)((char*)lV + la) = rv[ps];
  }
  __syncthreads();

  float m_r[2] = {-1e30f, -1e30f}, l_r[2] = {0.f, 0.f};
  f32x4 acc[2][4];
#pragma unroll
  for (int h = 0; h < 2; ++h)
#pragma unroll
    for (int nd = 0; nd < 4; ++nd) acc[h][nd] = (f32x4){0.f, 0.f, 0.f, 0.f};

  for (int jt = 0; jt <= jtmax; ++jt) {
    char* lKc = (char*)lK + (jt & 1) * 8192;
    char* lVc = (char*)lV + (jt & 1) * 8192;
    // issue next tile's loads early (consumed by commit at iter end)
    if (jt < jtmax) {
#pragma unroll
      for (int ps = 0; ps < 2; ++ps) {
        int r = ps * 32 + srow;
        rk[ps] = *(const bf16x8*)(Kp + (((size_t)bh * Tt + (jt + 1) * 64 + r) << 6) + scol);
        rv[ps] = *(const bf16x8*)(Vt + (((size_t)bh * 64 + r) << 11) + (jt + 1) * 64 + scol);
      }
    }
    // QK^T swapped, both halves share the K ds_reads
    f32x4 s[2][4];
#pragma unroll
    for (int h = 0; h < 2; ++h)
#pragma unroll
      for (int n = 0; n < 4; ++n) s[h][n] = (f32x4){0.f, 0.f, 0.f, 0.f};
#pragma unroll
    for (int n = 0; n < 4; ++n) {
      int rr = n * 16 + fr;
      int rsw = (rr & 7) << 4;
#pragma unroll
      for (int ks = 0; ks < 2; ++ks) {
        bf16x8 ak = *(const bf16x8*)(lKc + rr * 128 + ((ks * 64 + g * 16) ^ rsw));
        s[0][n] = __builtin_amdgcn_mfma_f32_16x16x32_bf16(ak, qf[0][ks], s[0][n], 0, 0, 0);
        s[1][n] = __builtin_amdgcn_mfma_f32_16x16x32_bf16(ak, qf[1][ks], s[1][n], 0, 0, 0);
      }
    }
    const bool needmask = (jt >= 2 * qt);
    const int kb = jt * 64;
#pragma unroll
    for (int h = 0; h < 2; ++h) {
      const int qglob = q0 + w * 32 + h * 16 + fr;
      const int prow = w * 32 + h * 16 + fr;
      const int psw = (prow & 7) << 4;
      float tm = -1e30f;
      if (needmask) {
#pragma unroll
        for (int n = 0; n < 4; ++n)
#pragma unroll
          for (int r = 0; r < 4; ++r) {
            float sv = s[h][n][r];
            if (kb + n * 16 + g * 4 + r > qglob) sv = -1e30f;
            s[h][n][r] = sv;
            tm = fmaxf(tm, sv);
          }
      } else {
#pragma unroll
        for (int n = 0; n < 4; ++n)
#pragma unroll
          for (int r = 0; r < 4; ++r) tm = fmaxf(tm, s[h][n][r]);
      }
      tm = fmaxf(tm, __shfl_xor(tm, 16));
      tm = fmaxf(tm, __shfl_xor(tm, 32));
      float mn = fmaxf(m_r[h], tm);
      float sc = exp2_fast(m_r[h] - mn);
      m_r[h] = mn;
      float rs = 0.f;
      u16x4v pw[4];
#pragma unroll
      for (int n = 0; n < 4; ++n)
#pragma unroll
        for (int r = 0; r < 4; ++r) {
          float p = exp2_fast(s[h][n][r] - mn);
          rs += p;
          pw[n][r] = f2b(p);
        }
      rs += __shfl_xor(rs, 16);
      rs += __shfl_xor(rs, 32);
      l_r[h] = l_r[h] * sc + rs;
      {
        char* base = (char*)lP + prow * 128;
#pragma unroll
        for (int n = 0; n < 4; ++n)
          *(u16x4v*)(base + ((32 * n + 8 * g) ^ psw)) = pw[n];
      }
      float scj[4];
#pragma unroll
      for (int j = 0; j < 4; ++j) scj[j] = __shfl(sc, g * 4 + j);
#pragma unroll
      for (int nd = 0; nd < 4; ++nd)
#pragma unroll
        for (int j = 0; j < 4; ++j) acc[h][nd][j] *= scj[j];
    }
    // PV: both halves share the V ds_reads
    bf16x8 pa[2][2];
#pragma unroll
    for (int h = 0; h < 2; ++h) {
      const int prow = w * 32 + h * 16 + fr;
      const int psw = (prow & 7) << 4;
#pragma unroll
      for (int ks = 0; ks < 2; ++ks)
        pa[h][ks] = *(const bf16x8*)((char*)lP + prow * 128 + ((ks * 64 + g * 16) ^ psw));
    }
#pragma unroll
    for (int nd = 0; nd < 4; ++nd) {
      int rr = nd * 16 + fr;
      int rsw = (rr & 7) << 4;
#pragma unroll
      for (int ks = 0; ks < 2; ++ks) {
        bf16x8 bv = *(const bf16x8*)(lVc + rr * 128 + ((ks * 64 + g * 16) ^ rsw));
        acc[0][nd] = __builtin_amdgcn_mfma_f32_16x16x32_bf16(pa[0][ks], bv, acc[0][nd], 0, 0, 0);
        acc[1][nd] = __builtin_amdgcn_mfma_f32_16x16x32_bf16(pa[1][ks], bv, acc[1][nd], 0, 0, 0);
      }
    }
    // commit next tile to the other buffer; single barrier per iter
    if (jt < jtmax) {
#pragma unroll
      for (int ps = 0; ps < 2; ++ps) {
        int r = ps * 32 + srow;
        int la = r * 128 + ((scol * 2) ^ ((r & 7) << 4));
        *(bf16x8*)((char*)lK + ((jt + 1) & 1) * 8192 + la) = rk[ps];
        *(bf16x8*)((char*)lV + ((jt + 1) & 1) * 8192 + la) = rv[ps];
      }
      __syncthreads();
    }
  }

  // epilogue: normalize, merge heads into AO [B,T,H] bf16
  const int b = bh >> 4, hh = bh & 15;
#pragma unroll
  for (int h = 0; h < 2; ++h) {
    float lj[4];
#pragma unroll
    for (int j = 0; j < 4; ++j) lj[j] = __shfl(l_r[h], g * 4 + j);
#pragma unroll
    for (int j = 0; j < 4; ++j) {
      float inv = 1.0f / lj[j];
      int qq = q0 + w * 32 + h * 16 + g * 4 + j;
      size_t base = (((size_t)b * Tt + qq) << 10) + hh * 64;
#pragma unroll
      for (int nd = 0; nd < 4; ++nd)
        AO[base + nd * 16 + fr] = f2b(acc[h][nd][j] * inv);
    }
  }
}

extern "C" void kernel_launch(void* const* d_in, const int* in_sizes, int n_in,
                              void* d_out, int out_size, void* d_ws, size_t ws_size,
                              hipStream_t stream) {
  const float* q   = (const float*)d_in[0];
  const float* k   = (const float*)d_in[1];
  const float* v   = (const float*)d_in[2];
  // d_in[3] = mask (known causal tril; unused)
  const float* wq  = (const float*)d_in[4];
  const float* bq  = (const float*)d_in[5];
  const float* wk  = (const float*)d_in[6];
  const float* bk  = (const float*)d_in[7];
  const float* wv  = (const float*)d_in[8];
  const float* bv  = (const float*)d_in[9];
  const float* wo  = (const float*)d_in[10];
  const float* bo  = (const float*)d_in[11];

  char* ws = (char*)d_ws;
  const size_t SZB = (size_t)Bb * Tt * Hh * 2;  // 8.39 MB
  const size_t WB  = (size_t)Hh * Hh * 2;       // 2.10 MB
  u16* qb  = (u16*)(ws);
  u16* kb  = (u16*)(ws + SZB);
  u16* vb  = (u16*)(ws + 2 * SZB);
  u16* wqb = (u16*)(ws + 3 * SZB);
  u16* wkb = (u16*)(ws + 3 * SZB + WB);
  u16* wvb = (u16*)(ws + 3 * SZB + 2 * WB);
  u16* wob = (u16*)(ws + 3 * SZB + 3 * WB);
  u16* Qp  = (u16*)(ws + 3 * SZB + 4 * WB);
  u16* Kp  = (u16*)(ws + 4 * SZB + 4 * WB);
  u16* Vt  = (u16*)(ws + 5 * SZB + 4 * WB);
  u16* AO  = qb;   // reuse (qb dead after projections)

  const int N4_IN = (Bb * Tt * Hh) / 4;
  const int N4_W  = (Hh * Hh) / 4;
  cvt3_kernel<<<dim3(512, 3), 256, 0, stream>>>(q, k, v, qb, kb, vb, N4_IN);
  cvt4_kernel<<<dim3(128, 4), 256, 0, stream>>>(wq, wk, wv, wo, wqb, wkb, wvb, wob, N4_W);

  proj_qkv_kernel<<<dim3(Hh / 128, (Bb * Tt) / 128, 3), 256, 0, stream>>>(
      qb, kb, vb, wqb, wkb, wvb, bq, bk, bv, Qp, Kp, Vt);

  attn_kernel<<<dim3(512), 256, 0, stream>>>(Qp, Kp, Vt, AO);

  gemm_out_kernel<<<dim3(Hh / 64, (Bb * Tt) / 128), 256, 0, stream>>>(
      AO, wob, bo, (float*)d_out);
}

// Round 7
// 131.591 us; speedup vs baseline: 1.7405x; 1.0099x over previous
//
#include <hip/hip_runtime.h>
#include <hip/hip_bf16.h>

// MHA: B=2 T=2048 H=1024 NH=16 HD=64. All matmuls via bf16 MFMA 16x16x32.
#define Bb 2
#define Tt 2048
#define Hh 1024
#define NHh 16

typedef short bf16x8 __attribute__((ext_vector_type(8)));
typedef float f32x4 __attribute__((ext_vector_type(4)));
typedef unsigned short u16;
typedef u16 u16x4v __attribute__((ext_vector_type(4)));

// 0.125 * log2(e): folded into w_q/b_q so softmax runs in exp2 domain.
#define QK_SCALE 0.180336880f

#if __has_builtin(__builtin_amdgcn_exp2f)
__device__ __forceinline__ float exp2_fast(float x) { return __builtin_amdgcn_exp2f(x); }
#else
__device__ __forceinline__ float exp2_fast(float x) { return __expf(x * 0.69314718f); }
#endif

__device__ __forceinline__ u16 f2b(float x) {
  unsigned u = __builtin_bit_cast(unsigned, x);
  u += 0x7FFFu + ((u >> 16) & 1u);   // RNE
  return (u16)(u >> 16);
}

// ---------------- fp32 -> bf16 conversion (batched, vectorized) ----------------
__global__ __launch_bounds__(256) void cvt3_kernel(const float* __restrict__ s0,
                                                   const float* __restrict__ s1,
                                                   const float* __restrict__ s2,
                                                   u16* __restrict__ d0,
                                                   u16* __restrict__ d1,
                                                   u16* __restrict__ d2, int n4) {
  const int which = blockIdx.y;
  const float* src = which == 0 ? s0 : which == 1 ? s1 : s2;
  u16* dst = which == 0 ? d0 : which == 1 ? d1 : d2;
  int i = blockIdx.x * blockDim.x + threadIdx.x;
  int stride = gridDim.x * blockDim.x;
  for (; i < n4; i += stride) {
    float4 v = ((const float4*)src)[i];
    u16x4v o;
    o.x = f2b(v.x); o.y = f2b(v.y); o.z = f2b(v.z); o.w = f2b(v.w);
    ((u16x4v*)dst)[i] = o;
  }
}

__global__ __launch_bounds__(256) void cvt4_kernel(const float* __restrict__ s0,
                                                   const float* __restrict__ s1,
                                                   const float* __restrict__ s2,
                                                   const float* __restrict__ s3,
                                                   u16* __restrict__ d0,
                                                   u16* __restrict__ d1,
                                                   u16* __restrict__ d2,
                                                   u16* __restrict__ d3, int n4) {
  const int which = blockIdx.y;
  const float* src = which == 0 ? s0 : which == 1 ? s1 : which == 2 ? s2 : s3;
  u16* dst = which == 0 ? d0 : which == 1 ? d1 : which == 2 ? d2 : d3;
  const float sc = (which == 0) ? QK_SCALE : 1.0f;   // w_q pre-scaled
  int i = blockIdx.x * blockDim.x + threadIdx.x;
  int stride = gridDim.x * blockDim.x;
  for (; i < n4; i += stride) {
    float4 v = ((const float4*)src)[i];
    u16x4v o;
    o.x = f2b(v.x * sc); o.y = f2b(v.y * sc); o.z = f2b(v.z * sc); o.w = f2b(v.w * sc);
    ((u16x4v*)dst)[i] = o;
  }
}

// ---------------- shared GEMM body: C[4096, NT] = A * W^T + bias*bscale --------
// 128 x (NF*32) tile, BK=64, 4 waves (2x2), reg-prefetch next K-tile.
// MODE 0: bf16 -> [B,NH,T,HD]; MODE 1: fp32 rm; MODE 2: bf16 -> V^T [B,NH,HD,T].
template<int NF, int MODE>
__device__ __forceinline__ void gemm_body(const u16* __restrict__ A,
                                          const u16* __restrict__ W,
                                          const float* __restrict__ bias, float bscale,
                                          void* __restrict__ Cout,
                                          u16* lA, u16* lB) {
  const int tid = threadIdx.x;
  const int lane = tid & 63;
  const int wid = tid >> 6;
  const int wr = wid >> 1, wc = wid & 1;
  const int g = lane >> 4, fr = lane & 15;
  const int mt = blockIdx.y, nt = blockIdx.x;
  constexpr int NT = NF * 32;

  f32x4 acc[4][NF];
#pragma unroll
  for (int m = 0; m < 4; ++m)
#pragma unroll
    for (int n = 0; n < NF; ++n) acc[m][n] = (f32x4){0.f, 0.f, 0.f, 0.f};

  const int srow = tid >> 3;        // 0..31
  const int scol = (tid & 7) * 8;   // element col 0..56

  bf16x8 ra[4], rb[NF];
#pragma unroll
  for (int ps = 0; ps < 4; ++ps)
    ra[ps] = *(const bf16x8*)(A + (size_t)(mt * 128 + ps * 32 + srow) * Hh + scol);
#pragma unroll
  for (int ps = 0; ps < NF; ++ps)
    rb[ps] = *(const bf16x8*)(W + (size_t)(nt * NT + ps * 32 + srow) * Hh + scol);
#pragma unroll
  for (int ps = 0; ps < 4; ++ps) {
    int r = ps * 32 + srow;
    *(bf16x8*)((char*)lA + r * 128 + ((scol * 2) ^ ((r & 7) << 4))) = ra[ps];
  }
#pragma unroll
  for (int ps = 0; ps < NF; ++ps) {
    int r = ps * 32 + srow;
    *(bf16x8*)((char*)lB + r * 128 + ((scol * 2) ^ ((r & 7) << 4))) = rb[ps];
  }
  __syncthreads();

  for (int kt = 0; kt < Hh; kt += 64) {
    if (kt + 64 < Hh) {
#pragma unroll
      for (int ps = 0; ps < 4; ++ps)
        ra[ps] = *(const bf16x8*)(A + (size_t)(mt * 128 + ps * 32 + srow) * Hh + kt + 64 + scol);
#pragma unroll
      for (int ps = 0; ps < NF; ++ps)
        rb[ps] = *(const bf16x8*)(W + (size_t)(nt * NT + ps * 32 + srow) * Hh + kt + 64 + scol);
    }
    bf16x8 af[4][2], bfv[NF][2];
#pragma unroll
    for (int m = 0; m < 4; ++m)
#pragma unroll
      for (int ks = 0; ks < 2; ++ks) {
        int r = wr * 64 + m * 16 + fr;
        af[m][ks] = *(const bf16x8*)((const char*)lA + r * 128 + ((ks * 64 + g * 16) ^ ((r & 7) << 4)));
      }
#pragma unroll
    for (int n = 0; n < NF; ++n)
#pragma unroll
      for (int ks = 0; ks < 2; ++ks) {
        int r = wc * (NT / 2) + n * 16 + fr;
        bfv[n][ks] = *(const bf16x8*)((const char*)lB + r * 128 + ((ks * 64 + g * 16) ^ ((r & 7) << 4)));
      }
#pragma unroll
    for (int m = 0; m < 4; ++m)
#pragma unroll
      for (int n = 0; n < NF; ++n)
#pragma unroll
        for (int ks = 0; ks < 2; ++ks)
          acc[m][n] = __builtin_amdgcn_mfma_f32_16x16x32_bf16(af[m][ks], bfv[n][ks],
                                                              acc[m][n], 0, 0, 0);
    if (kt + 64 < Hh) {
      __syncthreads();
#pragma unroll
      for (int ps = 0; ps < 4; ++ps) {
        int r = ps * 32 + srow;
        *(bf16x8*)((char*)lA + r * 128 + ((scol * 2) ^ ((r & 7) << 4))) = ra[ps];
      }
#pragma unroll
      for (int ps = 0; ps < NF; ++ps) {
        int r = ps * 32 + srow;
        *(bf16x8*)((char*)lB + r * 128 + ((scol * 2) ^ ((r & 7) << 4))) = rb[ps];
      }
      __syncthreads();
    }
  }

#pragma unroll
  for (int n = 0; n < NF; ++n) {
    int Cc = nt * NT + wc * (NT / 2) + n * 16 + fr;
    float bv = bias[Cc] * bscale;
#pragma unroll
    for (int m = 0; m < 4; ++m) {
#pragma unroll
      for (int j = 0; j < 4; ++j) {
        int R = mt * 128 + wr * 64 + m * 16 + g * 4 + j;
        float val = acc[m][n][j] + bv;
        if constexpr (MODE == 0) {
          int bb = R >> 11, t = R & (Tt - 1);
          int h = Cc >> 6, d = Cc & 63;
          ((u16*)Cout)[(((size_t)(bb * NHh + h) * Tt + t) << 6) + d] = f2b(val);
        } else if constexpr (MODE == 2) {
          int bb = R >> 11, t = R & (Tt - 1);
          int h = Cc >> 6, d = Cc & 63;
          ((u16*)Cout)[(((size_t)(bb * NHh + h) * 64 + d) << 11) + t] = f2b(val);
        } else {
          ((float*)Cout)[(size_t)R * Hh + Cc] = val;
        }
      }
    }
  }
}

__global__ __launch_bounds__(256, 3) void proj_qkv_kernel(
    const u16* __restrict__ qb, const u16* __restrict__ kb, const u16* __restrict__ vb,
    const u16* __restrict__ wqb, const u16* __restrict__ wkb, const u16* __restrict__ wvb,
    const float* __restrict__ biq, const float* __restrict__ bik, const float* __restrict__ biv,
    u16* __restrict__ Qp, u16* __restrict__ Kp, u16* __restrict__ Vt) {
  __shared__ u16 lA[128 * 64];
  __shared__ u16 lB[64 * 64];
  const int z = blockIdx.z;
  const u16* A = (z == 0) ? qb : (z == 1) ? kb : vb;
  const u16* W = (z == 0) ? wqb : (z == 1) ? wkb : wvb;
  const float* bi = (z == 0) ? biq : (z == 1) ? bik : biv;
  if (z == 2) gemm_body<2, 2>(A, W, bi, 1.0f, Vt, lA, lB);
  else if (z == 0) gemm_body<2, 0>(A, W, bi, QK_SCALE, Qp, lA, lB);
  else gemm_body<2, 0>(A, W, bi, 1.0f, Kp, lA, lB);
}

__global__ __launch_bounds__(256, 2) void gemm_out_kernel(
    const u16* __restrict__ A, const u16* __restrict__ W,
    const float* __restrict__ bias, float* __restrict__ Cout) {
  __shared__ u16 lA[128 * 64];
  __shared__ u16 lB[64 * 64];
  gemm_body<2, 1>(A, W, bias, 1.0f, Cout, lA, lB);
}

// ---------------- flash attention (causal) ----------------
// QBLK=128 (4 waves x 32 q-rows as 2 halves), KVBLK=64, dbuf K/V LDS, 1 barrier/iter.
// Swapped QK (mfma(K,Q)) -> full q-row in-lane; softmax in exp2 domain (Q pre-scaled).
// Cross-lane reduces via __shfl_xor (verified path). T13 defer-rescale skips the
// O-rescale + sc-broadcast when the running max didn't grow by >8 (exp2 domain).
__global__ __launch_bounds__(256, 2) void attn_kernel(const u16* __restrict__ Qp,
                                                      const u16* __restrict__ Kp,
                                                      const u16* __restrict__ Vt,
                                                      u16* __restrict__ AO) {
  __shared__ u16 lK[2 * 64 * 64];
  __shared__ u16 lV[2 * 64 * 64];
  __shared__ u16 lP[128 * 64];
  const int tid = threadIdx.x;
  const int lane = tid & 63;
  const int w = tid >> 6;
  const int g = lane >> 4, fr = lane & 15;
  // balanced remap: CU-resident pair (L, L+256) gets qt and 15-qt
  const int L = blockIdx.x;
  const int idx = L & 255, half = L >> 8;
  const int bh = (half ? 16 : 0) + (idx >> 4);
  const int qt = half ? 15 - (idx & 15) : (idx & 15);
  const int q0 = qt * 128;

  bf16x8 qf[2][2];
#pragma unroll
  for (int h = 0; h < 2; ++h) {
    const u16* qrow = Qp + (((size_t)bh * Tt + q0 + w * 32 + h * 16 + fr) << 6) + g * 8;
    qf[h][0] = *(const bf16x8*)(qrow);
    qf[h][1] = *(const bf16x8*)(qrow + 32);
  }

  const int srow = tid >> 3;
  const int scol = (tid & 7) * 8;
  const int jtmax = 2 * qt + 1;

  // prologue: tile 0 -> regs -> buf0
  bf16x8 rk[2], rv[2];
#pragma unroll
  for (int ps = 0; ps < 2; ++ps) {
    int r = ps * 32 + srow;
    rk[ps] = *(const bf16x8*)(Kp + (((size_t)bh * Tt + r) << 6) + scol);
    rv[ps] = *(const bf16x8*)(Vt + (((size_t)bh * 64 + r) << 11) + scol);
  }
#pragma unroll
  for (int ps = 0; ps < 2; ++ps) {
    int r = ps * 32 + srow;
    int la = r * 128 + ((scol * 2) ^ ((r & 7) << 4));
    *(bf16x8*)((char*)lK + la) = rk[ps];
    *(bf16x8*)((char*)lV + la) = rv[ps];
  }
  __syncthreads();

  float m_r[2] = {-1e30f, -1e30f}, l_r[2] = {0.f, 0.f};
  f32x4 acc[2][4];
#pragma unroll
  for (int h = 0; h < 2; ++h)
#pragma unroll
    for (int nd = 0; nd < 4; ++nd) acc[h][nd] = (f32x4){0.f, 0.f, 0.f, 0.f};

  for (int jt = 0; jt <= jtmax; ++jt) {
    char* lKc = (char*)lK + (jt & 1) * 8192;
    char* lVc = (char*)lV + (jt & 1) * 8192;
    // issue next tile's loads early (consumed by commit at iter end)
    if (jt < jtmax) {
#pragma unroll
      for (int ps = 0; ps < 2; ++ps) {
        int r = ps * 32 + srow;
        rk[ps] = *(const bf16x8*)(Kp + (((size_t)bh * Tt + (jt + 1) * 64 + r) << 6) + scol);
        rv[ps] = *(const bf16x8*)(Vt + (((size_t)bh * 64 + r) << 11) + (jt + 1) * 64 + scol);
      }
    }
    // QK^T swapped, both halves share the K ds_reads
    f32x4 s[2][4];
#pragma unroll
    for (int h = 0; h < 2; ++h)
#pragma unroll
      for (int n = 0; n < 4; ++n) s[h][n] = (f32x4){0.f, 0.f, 0.f, 0.f};
    __builtin_amdgcn_s_setprio(1);
#pragma unroll
    for (int n = 0; n < 4; ++n) {
      int rr = n * 16 + fr;
      int rsw = (rr & 7) << 4;
#pragma unroll
      for (int ks = 0; ks < 2; ++ks) {
        bf16x8 ak = *(const bf16x8*)(lKc + rr * 128 + ((ks * 64 + g * 16) ^ rsw));
        s[0][n] = __builtin_amdgcn_mfma_f32_16x16x32_bf16(ak, qf[0][ks], s[0][n], 0, 0, 0);
        s[1][n] = __builtin_amdgcn_mfma_f32_16x16x32_bf16(ak, qf[1][ks], s[1][n], 0, 0, 0);
      }
    }
    __builtin_amdgcn_s_setprio(0);
    const bool needmask = (jt >= 2 * qt);
    const int kb = jt * 64;
#pragma unroll
    for (int h = 0; h < 2; ++h) {
      const int qglob = q0 + w * 32 + h * 16 + fr;
      const int prow = w * 32 + h * 16 + fr;
      const int psw = (prow & 7) << 4;
      float tm = -1e30f;
      if (needmask) {
#pragma unroll
        for (int n = 0; n < 4; ++n)
#pragma unroll
          for (int r = 0; r < 4; ++r) {
            float sv = s[h][n][r];
            if (kb + n * 16 + g * 4 + r > qglob) sv = -1e30f;
            s[h][n][r] = sv;
            tm = fmaxf(tm, sv);
          }
      } else {
#pragma unroll
        for (int n = 0; n < 4; ++n)
#pragma unroll
          for (int r = 0; r < 4; ++r) tm = fmaxf(tm, s[h][n][r]);
      }
      tm = fmaxf(tm, __shfl_xor(tm, 16));
      tm = fmaxf(tm, __shfl_xor(tm, 32));
      // T13 defer-rescale: only rescale O/l when the row max grew materially.
      if (!__all(tm <= m_r[h] + 8.0f)) {
        float mn = fmaxf(m_r[h], tm);
        float sc = exp2_fast(m_r[h] - mn);
        m_r[h] = mn;
        l_r[h] *= sc;
        float scj[4];
#pragma unroll
        for (int j = 0; j < 4; ++j) scj[j] = __shfl(sc, g * 4 + j);
#pragma unroll
        for (int nd = 0; nd < 4; ++nd)
#pragma unroll
          for (int j = 0; j < 4; ++j) acc[h][nd][j] *= scj[j];
      }
      float rs = 0.f;
      u16x4v pw[4];
#pragma unroll
      for (int n = 0; n < 4; ++n)
#pragma unroll
        for (int r = 0; r < 4; ++r) {
          float p = exp2_fast(s[h][n][r] - m_r[h]);
          rs += p;
          pw[n][r] = f2b(p);
        }
      rs += __shfl_xor(rs, 16);
      rs += __shfl_xor(rs, 32);
      l_r[h] += rs;
      {
        char* base = (char*)lP + prow * 128;
#pragma unroll
        for (int n = 0; n < 4; ++n)
          *(u16x4v*)(base + ((32 * n + 8 * g) ^ psw)) = pw[n];
      }
    }
    // PV: both halves share the V ds_reads
    bf16x8 pa[2][2];
#pragma unroll
    for (int h = 0; h < 2; ++h) {
      const int prow = w * 32 + h * 16 + fr;
      const int psw = (prow & 7) << 4;
#pragma unroll
      for (int ks = 0; ks < 2; ++ks)
        pa[h][ks] = *(const bf16x8*)((char*)lP + prow * 128 + ((ks * 64 + g * 16) ^ psw));
    }
    __builtin_amdgcn_s_setprio(1);
#pragma unroll
    for (int nd = 0; nd < 4; ++nd) {
      int rr = nd * 16 + fr;
      int rsw = (rr & 7) << 4;
#pragma unroll
      for (int ks = 0; ks < 2; ++ks) {
        bf16x8 bv = *(const bf16x8*)(lVc + rr * 128 + ((ks * 64 + g * 16) ^ rsw));
        acc[0][nd] = __builtin_amdgcn_mfma_f32_16x16x32_bf16(pa[0][ks], bv, acc[0][nd], 0, 0, 0);
        acc[1][nd] = __builtin_amdgcn_mfma_f32_16x16x32_bf16(pa[1][ks], bv, acc[1][nd], 0, 0, 0);
      }
    }
    __builtin_amdgcn_s_setprio(0);
    // commit next tile to the other buffer; single barrier per iter
    if (jt < jtmax) {
#pragma unroll
      for (int ps = 0; ps < 2; ++ps) {
        int r = ps * 32 + srow;
        int la = r * 128 + ((scol * 2) ^ ((r & 7) << 4));
        *(bf16x8*)((char*)lK + ((jt + 1) & 1) * 8192 + la) = rk[ps];
        *(bf16x8*)((char*)lV + ((jt + 1) & 1) * 8192 + la) = rv[ps];
      }
      __syncthreads();
    }
  }

  // epilogue: normalize, merge heads into AO [B,T,H] bf16
  const int b = bh >> 4, hh = bh & 15;
#pragma unroll
  for (int h = 0; h < 2; ++h) {
    float lj[4];
#pragma unroll
    for (int j = 0; j < 4; ++j) lj[j] = __shfl(l_r[h], g * 4 + j);
#pragma unroll
    for (int j = 0; j < 4; ++j) {
      float inv = 1.0f / lj[j];
      int qq = q0 + w * 32 + h * 16 + g * 4 + j;
      size_t base = (((size_t)b * Tt + qq) << 10) + hh * 64;
#pragma unroll
      for (int nd = 0; nd < 4; ++nd)
        AO[base + nd * 16 + fr] = f2b(acc[h][nd][j] * inv);
    }
  }
}

extern "C" void kernel_launch(void* const* d_in, const int* in_sizes, int n_in,
                              void* d_out, int out_size, void* d_ws, size_t ws_size,
                              hipStream_t stream) {
  const float* q   = (const float*)d_in[0];
  const float* k   = (const float*)d_in[1];
  const float* v   = (const float*)d_in[2];
  // d_in[3] = mask (known causal tril; unused)
  const float* wq  = (const float*)d_in[4];
  const float* bq  = (const float*)d_in[5];
  const float* wk  = (const float*)d_in[6];
  const float* bk  = (const float*)d_in[7];
  const float* wv  = (const float*)d_in[8];
  const float* bv  = (const float*)d_in[9];
  const float* wo  = (const float*)d_in[10];
  const float* bo  = (const float*)d_in[11];

  char* ws = (char*)d_ws;
  const size_t SZB = (size_t)Bb * Tt * Hh * 2;  // 8.39 MB
  const size_t WB  = (size_t)Hh * Hh * 2;       // 2.10 MB
  u16* qb  = (u16*)(ws);
  u16* kb  = (u16*)(ws + SZB);
  u16* vb  = (u16*)(ws + 2 * SZB);
  u16* wqb = (u16*)(ws + 3 * SZB);
  u16* wkb = (u16*)(ws + 3 * SZB + WB);
  u16* wvb = (u16*)(ws + 3 * SZB + 2 * WB);
  u16* wob = (u16*)(ws + 3 * SZB + 3 * WB);
  u16* Qp  = (u16*)(ws + 3 * SZB + 4 * WB);
  u16* Kp  = (u16*)(ws + 4 * SZB + 4 * WB);
  u16* Vt  = (u16*)(ws + 5 * SZB + 4 * WB);
  u16* AO  = qb;   // reuse (qb dead after projections)

  const int N4_IN = (Bb * Tt * Hh) / 4;
  const int N4_W  = (Hh * Hh) / 4;
  cvt3_kernel<<<dim3(512, 3), 256, 0, stream>>>(q, k, v, qb, kb, vb, N4_IN);
  cvt4_kernel<<<dim3(128, 4), 256, 0, stream>>>(wq, wk, wv, wo, wqb, wkb, wvb, wob, N4_W);

  proj_qkv_kernel<<<dim3(Hh / 64, (Bb * Tt) / 128, 3), 256, 0, stream>>>(
      qb, kb, vb, wqb, wkb, wvb, bq, bk, bv, Qp, Kp, Vt);

  attn_kernel<<<dim3(512), 256, 0, stream>>>(Qp, Kp, Vt, AO);

  gemm_out_kernel<<<dim3(Hh / 64, (Bb * Tt) / 128), 256, 0, stream>>>(
      AO, wob, bo, (float*)d_out);
}